// Round 11
// baseline (327.811 us; speedup 1.0000x reference)
//
#include <hip/hip_runtime.h>
#include <hip/hip_bf16.h>
#include <stdint.h>
#include <stddef.h>

// Problem constants (fixed by the reference)
#define BB 2
#define NSEQ 2048
#define DM 1024
#define H 16
#define HD 128
#define D1 2048
#define NKI 16
#define RANKI 32
#define MROWS (BB * NSEQ)   // 4096 rows for all GEMMs
#define VPROWS 6144         // 2048 zero-pad | 2048 data | 2048 zero-pad
#define NTAP 28
#define NPAIR 13
#define NCHUNK 64
#define CLEN 32
#define GAMMA_F 0.999f
#define G_CL 0.9684910f     // 0.999^32 (chunk-length homogeneous decay)
// ln(0.999), for gamma^x = exp(x*ln_g)  (__exp2f collides with glibc; __expf is safe)
#define LN_G (-1.00050033e-3f)

// Sparse-tap positions of delta = (1 - g z)^2 * K  (K piecewise-linear * g^l,
// knots at l = 1 + 136.4j; integer knots j=5 (683), j=10 (1365) give 1 tap).
// NOTE: delta must remain fp32 everywhere — h[tau] = (tau+1)g^tau amplifies
// delta errors by up to ~368, so bf16 delta breaks the telescoping [R9].
// NOTE: do NOT XOR-swizzle the gemm LDS layout — the 4.19M bank-conflict
// counter is the global_load_lds DMA write port (inherent, also in m98's
// 874 TF kernel); R8's read pattern is already conflict-free, and permuted
// per-lane global addresses regressed uv-gemm 69->102 us [R10].
__device__ constexpr int TAPS[NTAP] = {
  1, 2, 138, 139, 274, 275, 411, 412, 547, 548, 684,
  820, 821, 956, 957, 1093, 1094, 1229, 1230, 1366,
  1502, 1503, 1638, 1639, 1775, 1776, 1911, 1912};
// pair decomposition: 13 (lead l, lag l+1) pairs + 2 singletons (684, 1366).
// lag value at step i == lead value at step i-1 -> register carry.
__device__ constexpr int LEADL[NPAIR] = {1, 138, 274, 411, 547, 820, 956, 1093, 1229, 1502, 1638, 1775, 1911};
__device__ constexpr int LEADI[NPAIR] = {0, 2, 4, 6, 8, 11, 13, 15, 17, 20, 22, 24, 26};
#define SGL0_L 684
#define SGL0_I 10
#define SGL1_L 1366
#define SGL1_I 19

typedef short short8 __attribute__((ext_vector_type(8)));
typedef float floatx4 __attribute__((ext_vector_type(4)));

__device__ __forceinline__ float bf2f(unsigned short u) {
  union { unsigned int i; float f; } v; v.i = ((unsigned int)u) << 16; return v.f;
}
__device__ __forceinline__ unsigned short f2bf(float f) {
  union { float f; unsigned int i; } v; v.f = f;
  unsigned int r = (v.i + 0x7FFFu + ((v.i >> 16) & 1u)) >> 16;
  return (unsigned short)r;
}
// unpack a packed pair of bf16 (little-endian: low ushort = even channel)
__device__ __forceinline__ float bflo(unsigned int p) {
  union { unsigned int i; float f; } v; v.i = p << 16; return v.f;
}
__device__ __forceinline__ float bfhi(unsigned int p) {
  union { unsigned int i; float f; } v; v.i = p & 0xffff0000u; return v.f;
}
// async 16B global->LDS DMA: lane i lands at (wave-uniform) l + i*16 bytes
__device__ __forceinline__ void async16(const unsigned short* g, unsigned short* l) {
  __builtin_amdgcn_global_load_lds(
      (const __attribute__((address_space(1))) unsigned int*)g,
      (__attribute__((address_space(3))) unsigned int*)l, 16, 0, 0);
}

// ---------------- fp32 -> bf16 elementwise convert (vectorized) ------------
__global__ __launch_bounds__(256) void cvt_kernel(const float* __restrict__ in,
                                                  unsigned short* __restrict__ out,
                                                  int n4) {
  int i = blockIdx.x * 256 + threadIdx.x;
  if (i >= n4) return;
  float4 f = ((const float4*)in)[i];
  ushort4 o;
  o.x = f2bf(f.x); o.y = f2bf(f.y); o.z = f2bf(f.z); o.w = f2bf(f.w);
  ((ushort4*)out)[i] = o;
}

// ------- fused transpose+convert: out_bf16[c][r] = in_f32[r][c] ------------
// grid.z selects among up to 2 (src,dst) pairs (fewer dispatches).
__global__ __launch_bounds__(256) void tpc_kernel(const float* __restrict__ inA,
                                                  unsigned short* __restrict__ outA,
                                                  const float* __restrict__ inB,
                                                  unsigned short* __restrict__ outB,
                                                  int rows, int cols) {
  __shared__ unsigned short t[32][33];
  const float* in = blockIdx.z ? inB : inA;
  unsigned short* out = blockIdx.z ? outB : outA;
  int bx = blockIdx.x * 32, by = blockIdx.y * 32;
  int tx = threadIdx.x, ty = threadIdx.y; // blockDim = (32,8)
#pragma unroll
  for (int j = 0; j < 32; j += 8)
    t[ty + j][tx] = f2bf(in[(size_t)(by + ty + j) * cols + bx + tx]);
  __syncthreads();
#pragma unroll
  for (int j = 0; j < 32; j += 8)
    out[(size_t)(bx + ty + j) * rows + by + tx] = t[tx][ty + j];
}

// ---- K(l) = interp(kind, l) * gamma^l on an LDS copy of kind --------------
__device__ __forceinline__ float KinterpL(const float* kk, int l, int d) {
  if (l < 1) return 0.0f;   // l > 2047 never queried (max tap 1912)
  float p = (float)(l - 1) * (15.0f / 2046.0f);
  int lo = (int)p; if (lo > 15) lo = 15;
  int hi = lo + 1; if (hi > 15) hi = 15;
  float w = p - (float)lo;
  float v = kk[lo * HD + d] * (1.0f - w) + kk[hi * HD + d] * w;
  return v * __powf(GAMMA_F, (float)l);
}

// ---- fused: kind = a@b per (head,dir) -> fp32 delta table at taps ---------
__global__ __launch_bounds__(256) void kdtab_kernel(const float* __restrict__ ap,
                                                    const float* __restrict__ bp,
                                                    const float* __restrict__ an,
                                                    const float* __restrict__ bn,
                                                    float* __restrict__ dtp,
                                                    float* __restrict__ dtn) {
  __shared__ float kk[NKI * HD];  // 8 KB
  int h = blockIdx.x, dir = blockIdx.y;
  const float* a = (dir ? an : ap) + h * NKI * RANKI;
  const float* b = (dir ? bn : bp) + h * RANKI * HD;
  for (int e = threadIdx.x; e < NKI * HD; e += 256) {
    int k = e >> 7, d = e & 127;
    float s = 0.0f;
#pragma unroll
    for (int r = 0; r < RANKI; ++r) s += a[k * RANKI + r] * b[r * HD + d];
    kk[e] = s;
  }
  __syncthreads();
  float* dt = (dir ? dtn : dtp) + (size_t)h * NTAP * HD;
  for (int e = threadIdx.x; e < NTAP * HD; e += 256) {
    int j = e >> 7, d = e & 127;
    int l = TAPS[j];
    float K0 = KinterpL(kk, l, d);
    float K1 = KinterpL(kk, l - 1, d);
    float K2 = KinterpL(kk, l - 2, d);
    dt[e] = K0 - 2.0f * GAMMA_F * K1 + (GAMMA_F * GAMMA_F) * K2;
  }
}

// ---------------- bf16 MFMA GEMM, double-buffered LDS ----------------------
// C = [silu](A @ Bt^T + bias). Tile = (MTILES*32) x 128, BK=32,
// global_load_lds width=16 (LDS unpadded, lane-ordered -- required by DMA).
// uv_mode: N=4096 fused u|v; n<2048 -> C (u), n>=2048 -> C2 (Vp, row-remapped).
template <int MTILES>
__global__ __launch_bounds__(256) void gemm_bf16(const unsigned short* __restrict__ A,
                                                 const unsigned short* __restrict__ Bt,
                                                 const float* __restrict__ bias,
                                                 const float* __restrict__ bias2,
                                                 void* __restrict__ C,
                                                 void* __restrict__ C2,
                                                 int M, int N, int K,
                                                 int do_silu, int c_fp32, int uv_mode) {
  __shared__ unsigned short Al[2][MTILES * 1024];   // MTILES*32 rows x 32 elems
  __shared__ unsigned short Bl[2][4096];            // 128 rows x 32 elems
  int m0 = blockIdx.y * (MTILES * 32), n0 = blockIdx.x * 128;
  int tid = threadIdx.x;
  int lane = tid & 63, w = tid >> 6;
  int rw = (w >> 1) * (MTILES * 16), cw = (w & 1) * 64;
  int q = lane >> 4, l16 = lane & 15;
  floatx4 acc[MTILES][4];
#pragma unroll
  for (int mt = 0; mt < MTILES; ++mt)
#pragma unroll
    for (int nt = 0; nt < 4; ++nt) acc[mt][nt] = (floatx4){0.f, 0.f, 0.f, 0.f};
  int grow = tid >> 2;            // row 0..63 within a 64-row segment
  int gcol = (tid & 3) * 8;       // k-offset (elems), plain lane order
  const unsigned short* A0 = A + (size_t)(m0 + grow) * K + gcol;
  const unsigned short* A1 = A0 + (size_t)64 * K;
  const unsigned short* B0 = Bt + (size_t)(n0 + grow) * K + gcol;
  const unsigned short* B1 = B0 + (size_t)64 * K;
  int woff = w * 512;             // wave-uniform LDS element base
  int nIter = K >> 5;
  // prologue: stage iter 0 into buffer 0
  async16(A0, &Al[0][woff]);
  if (MTILES == 4) async16(A1, &Al[0][2048 + woff]);
  async16(B0, &Bl[0][woff]);
  async16(B1, &Bl[0][2048 + woff]);
  int p = 0;
  for (int i = 0; i < nIter; ++i) {
    __syncthreads();   // drains vmcnt: buffer p staged; prev reads of p^1 done
    if (i + 1 < nIter) {           // prefetch i+1 into p^1, overlaps MFMA below
      int kn = (i + 1) << 5;
      async16(A0 + kn, &Al[p ^ 1][woff]);
      if (MTILES == 4) async16(A1 + kn, &Al[p ^ 1][2048 + woff]);
      async16(B0 + kn, &Bl[p ^ 1][woff]);
      async16(B1 + kn, &Bl[p ^ 1][2048 + woff]);
    }
    short8 af[MTILES], bfr[4];
#pragma unroll
    for (int i4 = 0; i4 < MTILES; ++i4)
      af[i4] = *(const short8*)(&Al[p][(rw + i4 * 16 + l16) * 32 + q * 8]);
#pragma unroll
    for (int i4 = 0; i4 < 4; ++i4)
      bfr[i4] = *(const short8*)(&Bl[p][(cw + i4 * 16 + l16) * 32 + q * 8]);
#pragma unroll
    for (int mt = 0; mt < MTILES; ++mt)
#pragma unroll
      for (int nt = 0; nt < 4; ++nt)
        acc[mt][nt] = __builtin_amdgcn_mfma_f32_16x16x32_bf16(af[mt], bfr[nt], acc[mt][nt], 0, 0, 0);
    p ^= 1;
  }
  // epilogue: D[row = q*4 + r][col = lane&15] per 16x16 tile (verified mapping)
  int isv = uv_mode && (n0 >= 2048);
  int ldc = uv_mode ? 2048 : N;
  int ncb = isv ? (n0 - 2048) : n0;
  const float* buse = isv ? bias2 : bias;
#pragma unroll
  for (int mt = 0; mt < MTILES; ++mt) {
#pragma unroll
    for (int nt = 0; nt < 4; ++nt) {
      int n = ncb + cw + nt * 16 + l16;
      float bsv = buse[n];
#pragma unroll
      for (int r = 0; r < 4; ++r) {
        int m = m0 + rw + mt * 16 + q * 4 + r;
        float val = acc[mt][nt][r] + bsv;
        if (do_silu) val = val / (1.0f + __expf(-val));
        if (isv) {
          size_t mrow = (size_t)(2048 + m + ((m >> 11) << 12));  // padded-V row
          ((unsigned short*)C2)[mrow * 2048 + n] = f2bf(val);
        } else if (c_fp32) {
          ((float*)C)[(size_t)m * ldc + n] = val;
        } else {
          ((unsigned short*)C)[(size_t)m * ldc + n] = f2bf(val);
        }
      }
    }
  }
}

// ---------------- chunked IIR scan (phase A) -------------------------------
// Per (dir, b, chunk, c-pair): zero-state local scan of CLEN steps.
//   F[t] = sum_j delta[h,j,d] * Vp[b, 2048 + t -/+ l_j, c]   (pads are zero)
// delta staged in LDS as fp32 (precision-critical); lag taps reuse lead
// values from the previous step via register carries: 15 V-loads/step not 28.
__global__ __launch_bounds__(256) void scan_chunks(const unsigned short* __restrict__ Vp,
                                                   const float* __restrict__ dp,
                                                   const float* __restrict__ dn,
                                                   unsigned short* __restrict__ ypl,
                                                   unsigned short* __restrict__ ynl,
                                                   float* __restrict__ Sy_ex,
                                                   float* __restrict__ SG_ex) {
  __shared__ float dsh[NTAP][512];   // 57344 B: fp32 delta for 512 channels
  int z = blockIdx.z;            // dir*2 + b
  int dir = z >> 1, b = z & 1;
  int chunk = blockIdx.y;
  int cBase = blockIdx.x * 512;
  int tid = threadIdx.x;
  {
    const float* dt = dir ? dn : dp;
    for (int e = tid; e < NTAP * 512; e += 256) {
      int j = e >> 9, cl = e & 511;
      int c = cBase + cl, h = c >> 7, d = c & 127;
      dsh[j][cl] = dt[((size_t)h * NTAP + j) * HD + d];
    }
  }
  __syncthreads();
  int c0 = cBase + tid * 2;      // two channels per thread
  int cl0 = tid * 2;
  const unsigned short* Vb = Vp + (size_t)b * VPROWS * D1 + c0;
  unsigned short* yl = (dir ? ynl : ypl) + (size_t)b * NSEQ * D1 + c0;
  float sy0 = 0.f, sy1 = 0.f, sg0 = 0.f, sg1 = 0.f;
  float carry0[NPAIR], carry1[NPAIR];
  if (!dir) {
    int t0 = chunk * CLEN;
    const unsigned short* Vrow = Vb + (size_t)(2048 + t0) * D1;
    // prime carries with step -1 lead values: row t0-1-l  (pad rows are zero)
#pragma unroll
    for (int p = 0; p < NPAIR; ++p) {
      unsigned int pk = *(const unsigned int*)(Vrow - (ptrdiff_t)(LEADL[p] + 1) * D1);
      carry0[p] = bflo(pk); carry1[p] = bfhi(pk);
    }
    int t = t0;
    for (int i = 0; i < CLEN; ++i) {
      float F0 = 0.f, F1 = 0.f;
#pragma unroll
      for (int p = 0; p < NPAIR; ++p) {
        unsigned int pk = *(const unsigned int*)(Vrow - (ptrdiff_t)LEADL[p] * D1);
        float vl0 = bflo(pk), vl1 = bfhi(pk);
        float2 dl = *(const float2*)&dsh[LEADI[p]][cl0];
        float2 dg = *(const float2*)&dsh[LEADI[p] + 1][cl0];
        F0 += dl.x * vl0 + dg.x * carry0[p];
        F1 += dl.y * vl1 + dg.y * carry1[p];
        carry0[p] = vl0; carry1[p] = vl1;
      }
      {
        unsigned int pk = *(const unsigned int*)(Vrow - (ptrdiff_t)SGL0_L * D1);
        float2 ds = *(const float2*)&dsh[SGL0_I][cl0];
        F0 += ds.x * bflo(pk); F1 += ds.y * bfhi(pk);
      }
      {
        unsigned int pk = *(const unsigned int*)(Vrow - (ptrdiff_t)SGL1_L * D1);
        float2 ds = *(const float2*)&dsh[SGL1_I][cl0];
        F0 += ds.x * bflo(pk); F1 += ds.y * bfhi(pk);
      }
      sg0 = GAMMA_F * sg0 + F0; sy0 = GAMMA_F * sy0 + sg0;
      sg1 = GAMMA_F * sg1 + F1; sy1 = GAMMA_F * sy1 + sg1;
      unsigned int pack = (unsigned int)f2bf(sy0) | ((unsigned int)f2bf(sy1) << 16);
      *(unsigned int*)(yl + (size_t)(t + i) * D1) = pack;
      Vrow += D1;
    }
  } else {
    int tstart = (NSEQ - 1) - chunk * CLEN;        // reversed time
    const unsigned short* Vrow = Vb + (size_t)(2048 + tstart) * D1;
#pragma unroll
    for (int p = 0; p < NPAIR; ++p) {
      unsigned int pk = *(const unsigned int*)(Vrow + (ptrdiff_t)(LEADL[p] + 1) * D1);
      carry0[p] = bflo(pk); carry1[p] = bfhi(pk);
    }
    for (int i = 0; i < CLEN; ++i) {
      float F0 = 0.f, F1 = 0.f;
#pragma unroll
      for (int p = 0; p < NPAIR; ++p) {
        unsigned int pk = *(const unsigned int*)(Vrow + (ptrdiff_t)LEADL[p] * D1);
        float vl0 = bflo(pk), vl1 = bfhi(pk);
        float2 dl = *(const float2*)&dsh[LEADI[p]][cl0];
        float2 dg = *(const float2*)&dsh[LEADI[p] + 1][cl0];
        F0 += dl.x * vl0 + dg.x * carry0[p];
        F1 += dl.y * vl1 + dg.y * carry1[p];
        carry0[p] = vl0; carry1[p] = vl1;
      }
      {
        unsigned int pk = *(const unsigned int*)(Vrow + (ptrdiff_t)SGL0_L * D1);
        float2 ds = *(const float2*)&dsh[SGL0_I][cl0];
        F0 += ds.x * bflo(pk); F1 += ds.y * bfhi(pk);
      }
      {
        unsigned int pk = *(const unsigned int*)(Vrow + (ptrdiff_t)SGL1_L * D1);
        float2 ds = *(const float2*)&dsh[SGL1_I][cl0];
        F0 += ds.x * bflo(pk); F1 += ds.y * bfhi(pk);
      }
      sg0 = GAMMA_F * sg0 + F0; sy0 = GAMMA_F * sy0 + sg0;
      sg1 = GAMMA_F * sg1 + F1; sy1 = GAMMA_F * sy1 + sg1;
      unsigned int pack = (unsigned int)f2bf(sy0) | ((unsigned int)f2bf(sy1) << 16);
      *(unsigned int*)(yl + (size_t)(tstart - i) * D1) = pack;
      Vrow -= D1;
    }
  }
  size_t sidx = ((size_t)z * NCHUNK + chunk) * D1 + c0;
  Sy_ex[sidx] = sy0; Sy_ex[sidx + 1] = sy1;
  SG_ex[sidx] = sg0; SG_ex[sidx + 1] = sg1;
}

// ---------------- chunk-state scan (phase B) -------------------------------
// entry(k+1) = local_exit(k) + homogeneous fixup from entry(k), L = CLEN.
__global__ __launch_bounds__(256) void state_scan(const float* __restrict__ Sy_ex,
                                                  const float* __restrict__ SG_ex,
                                                  float* __restrict__ Sy_in,
                                                  float* __restrict__ SG_in) {
  int idx = blockIdx.x * 256 + threadIdx.x;   // z*2048 + c, total 4*2048
  if (idx >= 4 * D1) return;
  int z = idx >> 11, c = idx & (D1 - 1);
  float ey = 0.f, eg = 0.f;
  for (int k = 0; k < NCHUNK; ++k) {
    size_t s = ((size_t)z * NCHUNK + k) * D1 + c;
    Sy_in[s] = ey; SG_in[s] = eg;
    float lex = Sy_ex[s], lgx = SG_ex[s];
    ey = lex + G_CL * (ey + (float)CLEN * eg);
    eg = lgx + G_CL * eg;
  }
}

// ---------------- combine + gate (phase C), 4 channels/thread --------------
// y = [y+loc + g^Dp (y_in + Dp G_in)] + [y-loc + g^Dn (...)] + tz*V;  g = U*y
__global__ __launch_bounds__(256) void combine_kernel(const unsigned short* __restrict__ ypl,
                                                      const unsigned short* __restrict__ ynl,
                                                      const unsigned short* __restrict__ Vp,
                                                      const float* __restrict__ Sy_in,
                                                      const float* __restrict__ SG_in,
                                                      const float* __restrict__ tz,
                                                      const unsigned short* __restrict__ U,
                                                      unsigned short* __restrict__ G) {
  int e = blockIdx.x * 256 + threadIdx.x;     // quad index over [b][t][c/4]
  int cq = e & (D1 / 4 - 1);
  int c0 = cq * 4;
  int r = e >> 9;
  int t = r & (NSEQ - 1);
  int b = r >> 11;
  int kp = t >> 5;  float dpD = (float)((t & 31) + 1);
  int tau = (NSEQ - 1) - t;
  int kn = tau >> 5; float dnD = (float)((tau & 31) + 1);
  float gp = __expf(dpD * LN_G);
  float gn = __expf(dnD * LN_G);
  size_t ix = (size_t)r * D1 + c0;
  size_t sp = ((size_t)(b) * NCHUNK + kp) * D1 + c0;          // z = b (pos)
  size_t sn = ((size_t)(2 + b) * NCHUNK + kn) * D1 + c0;      // z = 2+b (neg)
  uint2 pyl = *(const uint2*)(ypl + ix);
  uint2 pyn = *(const uint2*)(ynl + ix);
  uint2 pv  = *(const uint2*)(Vp + ((size_t)b * VPROWS + 2048 + t) * D1 + c0);
  uint2 pu  = *(const uint2*)(U + ix);
  float4 syp = *(const float4*)(Sy_in + sp);
  float4 sgp = *(const float4*)(SG_in + sp);
  float4 syn = *(const float4*)(Sy_in + sn);
  float4 sgn = *(const float4*)(SG_in + sn);
  float4 tzv = *(const float4*)(tz + c0);
  float yv[4], uv[4], vv[4];
  yv[0] = bflo(pyl.x) + gp * (syp.x + dpD * sgp.x) + bflo(pyn.x) + gn * (syn.x + dnD * sgn.x);
  yv[1] = bfhi(pyl.x) + gp * (syp.y + dpD * sgp.y) + bfhi(pyn.x) + gn * (syn.y + dnD * sgn.y);
  yv[2] = bflo(pyl.y) + gp * (syp.z + dpD * sgp.z) + bflo(pyn.y) + gn * (syn.z + dnD * sgn.z);
  yv[3] = bfhi(pyl.y) + gp * (syp.w + dpD * sgp.w) + bfhi(pyn.y) + gn * (syn.w + dnD * sgn.w);
  vv[0] = bflo(pv.x); vv[1] = bfhi(pv.x); vv[2] = bflo(pv.y); vv[3] = bfhi(pv.y);
  uv[0] = bflo(pu.x); uv[1] = bfhi(pu.x); uv[2] = bflo(pu.y); uv[3] = bfhi(pu.y);
  float tza[4] = {tzv.x, tzv.y, tzv.z, tzv.w};
  uint2 og;
  unsigned short g0 = f2bf(uv[0] * (yv[0] + tza[0] * vv[0]));
  unsigned short g1 = f2bf(uv[1] * (yv[1] + tza[1] * vv[1]));
  unsigned short g2 = f2bf(uv[2] * (yv[2] + tza[2] * vv[2]));
  unsigned short g3 = f2bf(uv[3] * (yv[3] + tza[3] * vv[3]));
  og.x = (unsigned int)g0 | ((unsigned int)g1 << 16);
  og.y = (unsigned int)g2 | ((unsigned int)g3 << 16);
  *(uint2*)(G + ix) = og;
}

// ---------------------------------------------------------------------------
extern "C" void kernel_launch(void* const* d_in, const int* in_sizes, int n_in,
                              void* d_out, int out_size, void* d_ws, size_t ws_size,
                              hipStream_t stream) {
  const float* x      = (const float*)d_in[0];
  const float* Wu     = (const float*)d_in[1];
  const float* bu     = (const float*)d_in[2];
  const float* Wv     = (const float*)d_in[3];
  const float* bv     = (const float*)d_in[4];
  const float* Wo     = (const float*)d_in[5];
  const float* bo     = (const float*)d_in[6];
  const float* a_pos  = (const float*)d_in[7];
  const float* b_pos  = (const float*)d_in[8];
  const float* a_neg  = (const float*)d_in[9];
  const float* b_neg  = (const float*)d_in[10];
  const float* t_zero = (const float*)d_in[11];
  float* out = (float*)d_out;

  char* ws = (char*)d_ws;
  unsigned short* x_bf  = (unsigned short*)ws; ws += (size_t)MROWS * DM * 2;        //  8 MB
  unsigned short* u_ws  = (unsigned short*)ws; ws += (size_t)MROWS * D1 * 2;        // 16 MB (g in-place)
  unsigned short* Vp    = (unsigned short*)ws; ws += (size_t)BB * VPROWS * D1 * 2;  // 48 MB padded V
  unsigned short* ypl   = (unsigned short*)ws; ws += (size_t)MROWS * D1 * 2;        // 16 MB
  unsigned short* ynl   = (unsigned short*)ws; ws += (size_t)MROWS * D1 * 2;        // 16 MB
  float* dtp   = (float*)ws; ws += (size_t)H * NTAP * HD * 4;                       // 229 KB (fp32!)
  float* dtn   = (float*)ws; ws += (size_t)H * NTAP * HD * 4;
  float* Sy_ex = (float*)ws; ws += (size_t)4 * NCHUNK * D1 * 4;                     // 2 MB each
  float* SG_ex = (float*)ws; ws += (size_t)4 * NCHUNK * D1 * 4;
  float* Sy_in = (float*)ws; ws += (size_t)4 * NCHUNK * D1 * 4;
  float* SG_in = (float*)ws; ws += (size_t)4 * NCHUNK * D1 * 4;
  // weight buffers alias ypl (disjoint lifetimes, stream-ordered)
  unsigned short* WT2 = ypl;
  unsigned short* WoT = ypl;

  dim3 tb256(256);
  dim3 tptb(32, 8);
  // zero the V pads (rows [0,2048) and [4096,6144) per b)
  (void)hipMemsetAsync(Vp, 0, (size_t)2048 * D1 * 2, stream);
  (void)hipMemsetAsync(Vp + (size_t)4096 * D1, 0, (size_t)2048 * D1 * 2, stream);
  (void)hipMemsetAsync(Vp + (size_t)VPROWS * D1, 0, (size_t)2048 * D1 * 2, stream);
  (void)hipMemsetAsync(Vp + ((size_t)VPROWS + 4096) * D1, 0, (size_t)2048 * D1 * 2, stream);
  // x -> bf16
  cvt_kernel<<<dim3((MROWS * DM / 4 + 255) / 256), tb256, 0, stream>>>(x, x_bf, MROWS * DM / 4);
  // low-rank kernel factors -> sparse fp32 delta tables (fused, both dirs)
  kdtab_kernel<<<dim3(H, 2), tb256, 0, stream>>>(a_pos, b_pos, a_neg, b_neg, dtp, dtn);
  // fused u|v gemm: Bt = [WuT ; WvT]  (N = 4096), 128x128 tiles
  tpc_kernel<<<dim3(D1 / 32, DM / 32, 2), tptb, 0, stream>>>(
      Wu, WT2, Wv, WT2 + (size_t)D1 * DM, DM, D1);
  gemm_bf16<4><<<dim3(2 * D1 / 128, MROWS / 128), tb256, 0, stream>>>(
      x_bf, WT2, bu, bv, u_ws, Vp, MROWS, 2 * D1, DM, 1, 0, 1);
  // IIR conv: chunked scans -> state scan -> combine+gate (in-place over u)
  scan_chunks<<<dim3(D1 / 512, NCHUNK, 4), tb256, 0, stream>>>(Vp, dtp, dtn, ypl, ynl, Sy_ex, SG_ex);
  state_scan<<<dim3((4 * D1 + 255) / 256), tb256, 0, stream>>>(Sy_ex, SG_ex, Sy_in, SG_in);
  combine_kernel<<<dim3((size_t)MROWS * D1 / 1024), tb256, 0, stream>>>(ypl, ynl, Vp, Sy_in, SG_in, t_zero, u_ws, u_ws);
  // out = g @ Wo + bo (fp32), 64x128 tiles -> 512 blocks = 2/CU
  tpc_kernel<<<dim3(DM / 32, D1 / 32, 1), tptb, 0, stream>>>(Wo, WoT, Wo, WoT, D1, DM);
  gemm_bf16<2><<<dim3(DM / 128, MROWS / 64), tb256, 0, stream>>>(
      u_ws, WoT, bo, bo, out, out, MROWS, DM, D1, 0, 1, 0);
}

// Round 12
// 307.345 us; speedup vs baseline: 1.0666x; 1.0666x over previous
//
#include <hip/hip_runtime.h>
#include <hip/hip_bf16.h>
#include <stdint.h>
#include <stddef.h>

// Problem constants (fixed by the reference)
#define BB 2
#define NSEQ 2048
#define DM 1024
#define H 16
#define HD 128
#define D1 2048
#define NKI 16
#define RANKI 32
#define MROWS (BB * NSEQ)   // 4096 rows for all GEMMs
#define VPROWS 6144         // 2048 zero-pad | 2048 data | 2048 zero-pad
#define NTAP 28
#define NPAIR 13
#define NCHUNK 128
#define CLEN 16
#define GAMMA_F 0.999f
#define G_CL 0.9841201f     // 0.999^16 (chunk-length homogeneous decay)
// ln(0.999), for gamma^x = exp(x*ln_g)  (__exp2f collides with glibc; __expf is safe)
#define LN_G (-1.00050033e-3f)

// Sparse-tap positions of delta = (1 - g z)^2 * K  (K piecewise-linear * g^l,
// knots at l = 1 + 136.4j; integer knots j=5 (683), j=10 (1365) give 1 tap).
// NOTE: delta must remain fp32 everywhere — h[tau] = (tau+1)g^tau amplifies
// delta errors by up to ~368, so bf16 delta breaks the telescoping [R9].
// NOTE: do NOT XOR-swizzle the gemm LDS layout — the 4.19M bank-conflict
// counter is the global_load_lds DMA write port (inherent); R8's read pattern
// is already conflict-free [R10/R11].
__device__ constexpr int TAPS[NTAP] = {
  1, 2, 138, 139, 274, 275, 411, 412, 547, 548, 684,
  820, 821, 956, 957, 1093, 1094, 1229, 1230, 1366,
  1502, 1503, 1638, 1639, 1775, 1776, 1911, 1912};
// pair decomposition: 13 (lead l, lag l+1) pairs + 2 singletons (684, 1366).
// lag value at step i == lead value at step i-1 -> register carry.
__device__ constexpr int LEADL[NPAIR] = {1, 138, 274, 411, 547, 820, 956, 1093, 1229, 1502, 1638, 1775, 1911};
__device__ constexpr int LEADI[NPAIR] = {0, 2, 4, 6, 8, 11, 13, 15, 17, 20, 22, 24, 26};
#define SGL0_L 684
#define SGL0_I 10
#define SGL1_L 1366
#define SGL1_I 19

typedef short short8 __attribute__((ext_vector_type(8)));
typedef float floatx4 __attribute__((ext_vector_type(4)));

__device__ __forceinline__ float bf2f(unsigned short u) {
  union { unsigned int i; float f; } v; v.i = ((unsigned int)u) << 16; return v.f;
}
__device__ __forceinline__ unsigned short f2bf(float f) {
  union { float f; unsigned int i; } v; v.f = f;
  unsigned int r = (v.i + 0x7FFFu + ((v.i >> 16) & 1u)) >> 16;
  return (unsigned short)r;
}
// unpack a packed pair of bf16 (little-endian: low ushort = even channel)
__device__ __forceinline__ float bflo(unsigned int p) {
  union { unsigned int i; float f; } v; v.i = p << 16; return v.f;
}
__device__ __forceinline__ float bfhi(unsigned int p) {
  union { unsigned int i; float f; } v; v.i = p & 0xffff0000u; return v.f;
}
// async 16B global->LDS DMA: lane i lands at (wave-uniform) l + i*16 bytes
__device__ __forceinline__ void async16(const unsigned short* g, unsigned short* l) {
  __builtin_amdgcn_global_load_lds(
      (const __attribute__((address_space(1))) unsigned int*)g,
      (__attribute__((address_space(3))) unsigned int*)l, 16, 0, 0);
}

// ------- prep: x fp32->bf16 convert + zero the 4 V pad regions (1 dispatch) -
#define CVT4 (MROWS * DM / 4)            // 1048576 float4->ushort4 units
#define PAD16 (4 * NSEQ * D1 / 8)        // 2097152 uint4 (8-short) pad writes
__global__ __launch_bounds__(256) void prep_kernel(const float* __restrict__ x,
                                                   unsigned short* __restrict__ x_bf,
                                                   unsigned short* __restrict__ Vp) {
  int i = blockIdx.x * 256 + threadIdx.x;
  if (i < CVT4) {
    float4 f = ((const float4*)x)[i];
    ushort4 o;
    o.x = f2bf(f.x); o.y = f2bf(f.y); o.z = f2bf(f.z); o.w = f2bf(f.w);
    ((ushort4*)x_bf)[i] = o;
  } else {
    int j = i - CVT4;
    if (j < PAD16) {
      int r = j >> 19;            // region 0..3, each 524288 uint4
      int off = j & 524287;
      // short-offsets of pad regions: rows [0,2048)+[4096,6144) per batch
      const size_t bases[4] = {0, (size_t)4096 * D1, (size_t)VPROWS * D1,
                               (size_t)VPROWS * D1 + (size_t)4096 * D1};
      uint4 z; z.x = z.y = z.z = z.w = 0u;
      ((uint4*)(Vp + bases[r]))[off] = z;
    }
  }
}

// ------- fused transpose+convert: out_bf16[c][r] = in_f32[r][c] ------------
// grid.z selects among up to 2 (src,dst) pairs (fewer dispatches).
__global__ __launch_bounds__(256) void tpc_kernel(const float* __restrict__ inA,
                                                  unsigned short* __restrict__ outA,
                                                  const float* __restrict__ inB,
                                                  unsigned short* __restrict__ outB,
                                                  int rows, int cols) {
  __shared__ unsigned short t[32][33];
  const float* in = blockIdx.z ? inB : inA;
  unsigned short* out = blockIdx.z ? outB : outA;
  int bx = blockIdx.x * 32, by = blockIdx.y * 32;
  int tx = threadIdx.x, ty = threadIdx.y; // blockDim = (32,8)
#pragma unroll
  for (int j = 0; j < 32; j += 8)
    t[ty + j][tx] = f2bf(in[(size_t)(by + ty + j) * cols + bx + tx]);
  __syncthreads();
#pragma unroll
  for (int j = 0; j < 32; j += 8)
    out[(size_t)(bx + ty + j) * rows + by + tx] = t[tx][ty + j];
}

// ---- K(l) = interp(kind, l) * gamma^l on an LDS copy of kind --------------
__device__ __forceinline__ float KinterpL(const float* kk, int l, int d) {
  if (l < 1) return 0.0f;   // l > 2047 never queried (max tap 1912)
  float p = (float)(l - 1) * (15.0f / 2046.0f);
  int lo = (int)p; if (lo > 15) lo = 15;
  int hi = lo + 1; if (hi > 15) hi = 15;
  float w = p - (float)lo;
  float v = kk[lo * HD + d] * (1.0f - w) + kk[hi * HD + d] * w;
  return v * __powf(GAMMA_F, (float)l);
}

// ---- fused: kind = a@b per (head,dir) -> fp32 delta table at taps ---------
__global__ __launch_bounds__(256) void kdtab_kernel(const float* __restrict__ ap,
                                                    const float* __restrict__ bp,
                                                    const float* __restrict__ an,
                                                    const float* __restrict__ bn,
                                                    float* __restrict__ dtp,
                                                    float* __restrict__ dtn) {
  __shared__ float kk[NKI * HD];  // 8 KB
  int h = blockIdx.x, dir = blockIdx.y;
  const float* a = (dir ? an : ap) + h * NKI * RANKI;
  const float* b = (dir ? bn : bp) + h * RANKI * HD;
  for (int e = threadIdx.x; e < NKI * HD; e += 256) {
    int k = e >> 7, d = e & 127;
    float s = 0.0f;
#pragma unroll
    for (int r = 0; r < RANKI; ++r) s += a[k * RANKI + r] * b[r * HD + d];
    kk[e] = s;
  }
  __syncthreads();
  float* dt = (dir ? dtn : dtp) + (size_t)h * NTAP * HD;
  for (int e = threadIdx.x; e < NTAP * HD; e += 256) {
    int j = e >> 7, d = e & 127;
    int l = TAPS[j];
    float K0 = KinterpL(kk, l, d);
    float K1 = KinterpL(kk, l - 1, d);
    float K2 = KinterpL(kk, l - 2, d);
    dt[e] = K0 - 2.0f * GAMMA_F * K1 + (GAMMA_F * GAMMA_F) * K2;
  }
}

// ---------------- bf16 MFMA GEMM, double-buffered LDS ----------------------
// C = [silu](A @ Bt^T + bias). Tile = (MTILES*32) x 128, BK=32,
// global_load_lds width=16 (LDS unpadded, lane-ordered -- required by DMA).
// uv_mode: N=4096 fused u|v; n<2048 -> C (u), n>=2048 -> C2 (Vp, row-remapped).
template <int MTILES>
__global__ __launch_bounds__(256) void gemm_bf16(const unsigned short* __restrict__ A,
                                                 const unsigned short* __restrict__ Bt,
                                                 const float* __restrict__ bias,
                                                 const float* __restrict__ bias2,
                                                 void* __restrict__ C,
                                                 void* __restrict__ C2,
                                                 int M, int N, int K,
                                                 int do_silu, int c_fp32, int uv_mode) {
  __shared__ unsigned short Al[2][MTILES * 1024];   // MTILES*32 rows x 32 elems
  __shared__ unsigned short Bl[2][4096];            // 128 rows x 32 elems
  int m0 = blockIdx.y * (MTILES * 32), n0 = blockIdx.x * 128;
  int tid = threadIdx.x;
  int lane = tid & 63, w = tid >> 6;
  int rw = (w >> 1) * (MTILES * 16), cw = (w & 1) * 64;
  int q = lane >> 4, l16 = lane & 15;
  floatx4 acc[MTILES][4];
#pragma unroll
  for (int mt = 0; mt < MTILES; ++mt)
#pragma unroll
    for (int nt = 0; nt < 4; ++nt) acc[mt][nt] = (floatx4){0.f, 0.f, 0.f, 0.f};
  int grow = tid >> 2;            // row 0..63 within a 64-row segment
  int gcol = (tid & 3) * 8;       // k-offset (elems), plain lane order
  const unsigned short* A0 = A + (size_t)(m0 + grow) * K + gcol;
  const unsigned short* A1 = A0 + (size_t)64 * K;
  const unsigned short* B0 = Bt + (size_t)(n0 + grow) * K + gcol;
  const unsigned short* B1 = B0 + (size_t)64 * K;
  int woff = w * 512;             // wave-uniform LDS element base
  int nIter = K >> 5;
  // prologue: stage iter 0 into buffer 0
  async16(A0, &Al[0][woff]);
  if (MTILES == 4) async16(A1, &Al[0][2048 + woff]);
  async16(B0, &Bl[0][woff]);
  async16(B1, &Bl[0][2048 + woff]);
  int p = 0;
  for (int i = 0; i < nIter; ++i) {
    __syncthreads();   // drains vmcnt: buffer p staged; prev reads of p^1 done
    if (i + 1 < nIter) {           // prefetch i+1 into p^1, overlaps MFMA below
      int kn = (i + 1) << 5;
      async16(A0 + kn, &Al[p ^ 1][woff]);
      if (MTILES == 4) async16(A1 + kn, &Al[p ^ 1][2048 + woff]);
      async16(B0 + kn, &Bl[p ^ 1][woff]);
      async16(B1 + kn, &Bl[p ^ 1][2048 + woff]);
    }
    short8 af[MTILES], bfr[4];
#pragma unroll
    for (int i4 = 0; i4 < MTILES; ++i4)
      af[i4] = *(const short8*)(&Al[p][(rw + i4 * 16 + l16) * 32 + q * 8]);
#pragma unroll
    for (int i4 = 0; i4 < 4; ++i4)
      bfr[i4] = *(const short8*)(&Bl[p][(cw + i4 * 16 + l16) * 32 + q * 8]);
#pragma unroll
    for (int mt = 0; mt < MTILES; ++mt)
#pragma unroll
      for (int nt = 0; nt < 4; ++nt)
        acc[mt][nt] = __builtin_amdgcn_mfma_f32_16x16x32_bf16(af[mt], bfr[nt], acc[mt][nt], 0, 0, 0);
    p ^= 1;
  }
  // epilogue: D[row = q*4 + r][col = lane&15] per 16x16 tile (verified mapping)
  int isv = uv_mode && (n0 >= 2048);
  int ldc = uv_mode ? 2048 : N;
  int ncb = isv ? (n0 - 2048) : n0;
  const float* buse = isv ? bias2 : bias;
#pragma unroll
  for (int mt = 0; mt < MTILES; ++mt) {
#pragma unroll
    for (int nt = 0; nt < 4; ++nt) {
      int n = ncb + cw + nt * 16 + l16;
      float bsv = buse[n];
#pragma unroll
      for (int r = 0; r < 4; ++r) {
        int m = m0 + rw + mt * 16 + q * 4 + r;
        float val = acc[mt][nt][r] + bsv;
        if (do_silu) val = val / (1.0f + __expf(-val));
        if (isv) {
          size_t mrow = (size_t)(2048 + m + ((m >> 11) << 12));  // padded-V row
          ((unsigned short*)C2)[mrow * 2048 + n] = f2bf(val);
        } else if (c_fp32) {
          ((float*)C)[(size_t)m * ldc + n] = val;
        } else {
          ((unsigned short*)C)[(size_t)m * ldc + n] = f2bf(val);
        }
      }
    }
  }
}

// ---------------- chunked IIR scan (phase A) -------------------------------
// Per (dir, b, chunk, c-pair): zero-state local scan of CLEN steps.
//   F[t] = sum_j delta[h,j,d] * Vp[b, 2048 + t -/+ l_j, c]   (pads are zero)
// delta held in REGISTERS (56 VGPR; launch_bounds(256,1) so the allocator
// keeps them — R8's LDS version issued 28 ds_read_b64/step, the LDS pipe was
// the limiter and 57KB LDS capped occupancy at 8 waves/CU). Lag taps reuse
// lead values from the previous step via carries: 15 VMEM loads/step not 28.
__global__ __launch_bounds__(256, 1) void scan_chunks(const unsigned short* __restrict__ Vp,
                                                      const float* __restrict__ dp,
                                                      const float* __restrict__ dn,
                                                      unsigned short* __restrict__ ypl,
                                                      unsigned short* __restrict__ ynl,
                                                      float* __restrict__ Sy_ex,
                                                      float* __restrict__ SG_ex) {
  int z = blockIdx.z;            // dir*2 + b
  int dir = z >> 1, b = z & 1;
  int chunk = blockIdx.y;
  int c0 = blockIdx.x * 512 + threadIdx.x * 2;   // two channels per thread
  int h = c0 >> 7, d = c0 & 127;
  const float* dt = (dir ? dn : dp) + ((size_t)h * NTAP) * HD + d;
  float2 dreg[NTAP];
#pragma unroll
  for (int j = 0; j < NTAP; ++j) dreg[j] = *(const float2*)(dt + j * HD);
  const unsigned short* Vb = Vp + (size_t)b * VPROWS * D1 + c0;
  unsigned short* yl = (dir ? ynl : ypl) + (size_t)b * NSEQ * D1 + c0;
  float sy0 = 0.f, sy1 = 0.f, sg0 = 0.f, sg1 = 0.f;
  float carry0[NPAIR], carry1[NPAIR];
  if (!dir) {
    int t0 = chunk * CLEN;
    const unsigned short* Vrow = Vb + (size_t)(2048 + t0) * D1;
    // prime carries with step -1 lead values: row t0-1-l  (pad rows are zero)
#pragma unroll
    for (int p = 0; p < NPAIR; ++p) {
      unsigned int pk = *(const unsigned int*)(Vrow - (ptrdiff_t)(LEADL[p] + 1) * D1);
      carry0[p] = bflo(pk); carry1[p] = bfhi(pk);
    }
    for (int i = 0; i < CLEN; ++i) {
      float F0 = 0.f, F1 = 0.f;
#pragma unroll
      for (int p = 0; p < NPAIR; ++p) {
        unsigned int pk = *(const unsigned int*)(Vrow - (ptrdiff_t)LEADL[p] * D1);
        float vl0 = bflo(pk), vl1 = bfhi(pk);
        F0 += dreg[LEADI[p]].x * vl0 + dreg[LEADI[p] + 1].x * carry0[p];
        F1 += dreg[LEADI[p]].y * vl1 + dreg[LEADI[p] + 1].y * carry1[p];
        carry0[p] = vl0; carry1[p] = vl1;
      }
      {
        unsigned int pk = *(const unsigned int*)(Vrow - (ptrdiff_t)SGL0_L * D1);
        F0 += dreg[SGL0_I].x * bflo(pk); F1 += dreg[SGL0_I].y * bfhi(pk);
      }
      {
        unsigned int pk = *(const unsigned int*)(Vrow - (ptrdiff_t)SGL1_L * D1);
        F0 += dreg[SGL1_I].x * bflo(pk); F1 += dreg[SGL1_I].y * bfhi(pk);
      }
      sg0 = GAMMA_F * sg0 + F0; sy0 = GAMMA_F * sy0 + sg0;
      sg1 = GAMMA_F * sg1 + F1; sy1 = GAMMA_F * sy1 + sg1;
      unsigned int pack = (unsigned int)f2bf(sy0) | ((unsigned int)f2bf(sy1) << 16);
      *(unsigned int*)(yl + (size_t)(t0 + i) * D1) = pack;
      Vrow += D1;
    }
  } else {
    int tstart = (NSEQ - 1) - chunk * CLEN;        // reversed time
    const unsigned short* Vrow = Vb + (size_t)(2048 + tstart) * D1;
#pragma unroll
    for (int p = 0; p < NPAIR; ++p) {
      unsigned int pk = *(const unsigned int*)(Vrow + (ptrdiff_t)(LEADL[p] + 1) * D1);
      carry0[p] = bflo(pk); carry1[p] = bfhi(pk);
    }
    for (int i = 0; i < CLEN; ++i) {
      float F0 = 0.f, F1 = 0.f;
#pragma unroll
      for (int p = 0; p < NPAIR; ++p) {
        unsigned int pk = *(const unsigned int*)(Vrow + (ptrdiff_t)LEADL[p] * D1);
        float vl0 = bflo(pk), vl1 = bfhi(pk);
        F0 += dreg[LEADI[p]].x * vl0 + dreg[LEADI[p] + 1].x * carry0[p];
        F1 += dreg[LEADI[p]].y * vl1 + dreg[LEADI[p] + 1].y * carry1[p];
        carry0[p] = vl0; carry1[p] = vl1;
      }
      {
        unsigned int pk = *(const unsigned int*)(Vrow + (ptrdiff_t)SGL0_L * D1);
        F0 += dreg[SGL0_I].x * bflo(pk); F1 += dreg[SGL0_I].y * bfhi(pk);
      }
      {
        unsigned int pk = *(const unsigned int*)(Vrow + (ptrdiff_t)SGL1_L * D1);
        F0 += dreg[SGL1_I].x * bflo(pk); F1 += dreg[SGL1_I].y * bfhi(pk);
      }
      sg0 = GAMMA_F * sg0 + F0; sy0 = GAMMA_F * sy0 + sg0;
      sg1 = GAMMA_F * sg1 + F1; sy1 = GAMMA_F * sy1 + sg1;
      unsigned int pack = (unsigned int)f2bf(sy0) | ((unsigned int)f2bf(sy1) << 16);
      *(unsigned int*)(yl + (size_t)(tstart - i) * D1) = pack;
      Vrow -= D1;
    }
  }
  size_t sidx = ((size_t)z * NCHUNK + chunk) * D1 + c0;
  Sy_ex[sidx] = sy0; Sy_ex[sidx + 1] = sy1;
  SG_ex[sidx] = sg0; SG_ex[sidx + 1] = sg1;
}

// ---------------- chunk-state scan (phase B) -------------------------------
// entry(k+1) = local_exit(k) + homogeneous fixup from entry(k), L = CLEN.
__global__ __launch_bounds__(256) void state_scan(const float* __restrict__ Sy_ex,
                                                  const float* __restrict__ SG_ex,
                                                  float* __restrict__ Sy_in,
                                                  float* __restrict__ SG_in) {
  int idx = blockIdx.x * 256 + threadIdx.x;   // z*2048 + c, total 4*2048
  if (idx >= 4 * D1) return;
  int z = idx >> 11, c = idx & (D1 - 1);
  float ey = 0.f, eg = 0.f;
  for (int k = 0; k < NCHUNK; ++k) {
    size_t s = ((size_t)z * NCHUNK + k) * D1 + c;
    Sy_in[s] = ey; SG_in[s] = eg;
    float lex = Sy_ex[s], lgx = SG_ex[s];
    ey = lex + G_CL * (ey + (float)CLEN * eg);
    eg = lgx + G_CL * eg;
  }
}

// ---------------- combine + gate (phase C), 4 channels/thread --------------
// y = [y+loc + g^Dp (y_in + Dp G_in)] + [y-loc + g^Dn (...)] + tz*V;  g = U*y
__global__ __launch_bounds__(256) void combine_kernel(const unsigned short* __restrict__ ypl,
                                                      const unsigned short* __restrict__ ynl,
                                                      const unsigned short* __restrict__ Vp,
                                                      const float* __restrict__ Sy_in,
                                                      const float* __restrict__ SG_in,
                                                      const float* __restrict__ tz,
                                                      const unsigned short* __restrict__ U,
                                                      unsigned short* __restrict__ G) {
  int e = blockIdx.x * 256 + threadIdx.x;     // quad index over [b][t][c/4]
  int cq = e & (D1 / 4 - 1);
  int c0 = cq * 4;
  int r = e >> 9;
  int t = r & (NSEQ - 1);
  int b = r >> 11;
  int kp = t >> 4;  float dpD = (float)((t & 15) + 1);
  int tau = (NSEQ - 1) - t;
  int kn = tau >> 4; float dnD = (float)((tau & 15) + 1);
  float gp = __expf(dpD * LN_G);
  float gn = __expf(dnD * LN_G);
  size_t ix = (size_t)r * D1 + c0;
  size_t sp = ((size_t)(b) * NCHUNK + kp) * D1 + c0;          // z = b (pos)
  size_t sn = ((size_t)(2 + b) * NCHUNK + kn) * D1 + c0;      // z = 2+b (neg)
  uint2 pyl = *(const uint2*)(ypl + ix);
  uint2 pyn = *(const uint2*)(ynl + ix);
  uint2 pv  = *(const uint2*)(Vp + ((size_t)b * VPROWS + 2048 + t) * D1 + c0);
  uint2 pu  = *(const uint2*)(U + ix);
  float4 syp = *(const float4*)(Sy_in + sp);
  float4 sgp = *(const float4*)(SG_in + sp);
  float4 syn = *(const float4*)(Sy_in + sn);
  float4 sgn = *(const float4*)(SG_in + sn);
  float4 tzv = *(const float4*)(tz + c0);
  float yv[4], uv[4], vv[4];
  yv[0] = bflo(pyl.x) + gp * (syp.x + dpD * sgp.x) + bflo(pyn.x) + gn * (syn.x + dnD * sgn.x);
  yv[1] = bfhi(pyl.x) + gp * (syp.y + dpD * sgp.y) + bfhi(pyn.x) + gn * (syn.y + dnD * sgn.y);
  yv[2] = bflo(pyl.y) + gp * (syp.z + dpD * sgp.z) + bflo(pyn.y) + gn * (syn.z + dnD * sgn.z);
  yv[3] = bfhi(pyl.y) + gp * (syp.w + dpD * sgp.w) + bfhi(pyn.y) + gn * (syn.w + dnD * sgn.w);
  vv[0] = bflo(pv.x); vv[1] = bfhi(pv.x); vv[2] = bflo(pv.y); vv[3] = bfhi(pv.y);
  uv[0] = bflo(pu.x); uv[1] = bfhi(pu.x); uv[2] = bflo(pu.y); uv[3] = bfhi(pu.y);
  float tza[4] = {tzv.x, tzv.y, tzv.z, tzv.w};
  uint2 og;
  unsigned short g0 = f2bf(uv[0] * (yv[0] + tza[0] * vv[0]));
  unsigned short g1 = f2bf(uv[1] * (yv[1] + tza[1] * vv[1]));
  unsigned short g2 = f2bf(uv[2] * (yv[2] + tza[2] * vv[2]));
  unsigned short g3 = f2bf(uv[3] * (yv[3] + tza[3] * vv[3]));
  og.x = (unsigned int)g0 | ((unsigned int)g1 << 16);
  og.y = (unsigned int)g2 | ((unsigned int)g3 << 16);
  *(uint2*)(G + ix) = og;
}

// ---------------------------------------------------------------------------
extern "C" void kernel_launch(void* const* d_in, const int* in_sizes, int n_in,
                              void* d_out, int out_size, void* d_ws, size_t ws_size,
                              hipStream_t stream) {
  const float* x      = (const float*)d_in[0];
  const float* Wu     = (const float*)d_in[1];
  const float* bu     = (const float*)d_in[2];
  const float* Wv     = (const float*)d_in[3];
  const float* bv     = (const float*)d_in[4];
  const float* Wo     = (const float*)d_in[5];
  const float* bo     = (const float*)d_in[6];
  const float* a_pos  = (const float*)d_in[7];
  const float* b_pos  = (const float*)d_in[8];
  const float* a_neg  = (const float*)d_in[9];
  const float* b_neg  = (const float*)d_in[10];
  const float* t_zero = (const float*)d_in[11];
  float* out = (float*)d_out;

  char* ws = (char*)d_ws;
  unsigned short* x_bf  = (unsigned short*)ws; ws += (size_t)MROWS * DM * 2;        //  8 MB
  unsigned short* u_ws  = (unsigned short*)ws; ws += (size_t)MROWS * D1 * 2;        // 16 MB (g in-place)
  unsigned short* Vp    = (unsigned short*)ws; ws += (size_t)BB * VPROWS * D1 * 2;  // 48 MB padded V
  unsigned short* ypl   = (unsigned short*)ws; ws += (size_t)MROWS * D1 * 2;        // 16 MB
  unsigned short* ynl   = (unsigned short*)ws; ws += (size_t)MROWS * D1 * 2;        // 16 MB
  float* dtp   = (float*)ws; ws += (size_t)H * NTAP * HD * 4;                       // 229 KB (fp32!)
  float* dtn   = (float*)ws; ws += (size_t)H * NTAP * HD * 4;
  float* Sy_in = (float*)ws; ws += (size_t)4 * NCHUNK * D1 * 4;                     // 4 MB each
  float* SG_in = (float*)ws; ws += (size_t)4 * NCHUNK * D1 * 4;
  // exit-state arrays alias x_bf (dead after the uv-gemm, 8 MB = exactly fits)
  float* Sy_ex = (float*)x_bf;
  float* SG_ex = (float*)x_bf + (size_t)4 * NCHUNK * D1;
  // weight buffers alias ypl (disjoint lifetimes, stream-ordered)
  unsigned short* WT2 = ypl;
  unsigned short* WoT = ypl;

  dim3 tb256(256);
  dim3 tptb(32, 8);
  // prep: x->bf16 + zero V pads (one dispatch replaces cvt + 4 memsets)
  prep_kernel<<<dim3((CVT4 + PAD16 + 255) / 256), tb256, 0, stream>>>(x, x_bf, Vp);
  // low-rank kernel factors -> sparse fp32 delta tables (fused, both dirs)
  kdtab_kernel<<<dim3(H, 2), tb256, 0, stream>>>(a_pos, b_pos, a_neg, b_neg, dtp, dtn);
  // fused u|v gemm: Bt = [WuT ; WvT]  (N = 4096), 128x128 tiles
  tpc_kernel<<<dim3(D1 / 32, DM / 32, 2), tptb, 0, stream>>>(
      Wu, WT2, Wv, WT2 + (size_t)D1 * DM, DM, D1);
  gemm_bf16<4><<<dim3(2 * D1 / 128, MROWS / 128), tb256, 0, stream>>>(
      x_bf, WT2, bu, bv, u_ws, Vp, MROWS, 2 * D1, DM, 1, 0, 1);
  // IIR conv: chunked scans -> state scan -> combine+gate (in-place over u)
  scan_chunks<<<dim3(D1 / 512, NCHUNK, 4), tb256, 0, stream>>>(Vp, dtp, dtn, ypl, ynl, Sy_ex, SG_ex);
  state_scan<<<dim3((4 * D1 + 255) / 256), tb256, 0, stream>>>(Sy_ex, SG_ex, Sy_in, SG_in);
  combine_kernel<<<dim3((size_t)MROWS * D1 / 1024), tb256, 0, stream>>>(ypl, ynl, Vp, Sy_in, SG_in, t_zero, u_ws, u_ws);
  // out = g @ Wo + bo (fp32), 64x128 tiles -> 512 blocks = 2/CU
  tpc_kernel<<<dim3(DM / 32, D1 / 32, 1), tptb, 0, stream>>>(Wo, WoT, Wo, WoT, D1, DM);
  gemm_bf16<2><<<dim3(DM / 128, MROWS / 64), tb256, 0, stream>>>(
      u_ws, WoT, bo, bo, out, out, MROWS, DM, D1, 0, 1, 0);
}